// Round 14
// baseline (238.379 us; speedup 1.0000x reference)
//
#include <hip/hip_runtime.h>
#include <hip/hip_bf16.h>
#include <math.h>

#define DF 128
#define PSPLIT 4
#define CHUNK 8192
#define NBK 256
#define CAP 6144   // per-bucket edge capacity (mean ~4082 for E=800K/196 buckets; huge margin)
#define LEAKY(x) ((x) > 0.f ? (x) : 0.01f * (x))

typedef __attribute__((ext_vector_type(8))) short short8v;   // 8 bf16 in 4 VGPRs
typedef __attribute__((ext_vector_type(4))) float f32x4;
typedef __attribute__((ext_vector_type(4))) unsigned short u16x4;
typedef __attribute__((ext_vector_type(8))) unsigned short u16x8;

static __device__ __forceinline__ unsigned short f2bf(float f) {
  unsigned u = __float_as_uint(f);
  unsigned r = u + 0x7fffu + ((u >> 16) & 1u);   // RNE
  return (unsigned short)(r >> 16);
}
static __device__ __forceinline__ float bf2f(unsigned short b) {
  return __uint_as_float(((unsigned)b) << 16);
}

// fused A: [0,PB) pool counts; [PB,PB+WB) castW (fragment order)
__global__ void fusedA_k(const int* __restrict__ post_idx, const int* __restrict__ image_idx,
                         const int* __restrict__ batch, int* __restrict__ pcnt,
                         int* __restrict__ icnt,
                         const float* __restrict__ W, unsigned short* __restrict__ Wb,
                         int NP, int NI, int wTotal, int PB) {
  int b = blockIdx.x;
  if (b < PB) {
    int i = b * 256 + threadIdx.x;
    if (i < NP) atomicAdd(&pcnt[batch[post_idx[i]]], 1);
    else if (i < NP + NI) atomicAdd(&icnt[batch[image_idx[i - NP]]], 1);
  } else {
    int i = (b - PB) * 256 + threadIdx.x;
    if (i < wTotal) {
      int layer = i >> 14, o = i & 16383;
      int j = o & 7, l = (o >> 3) & 63, ks = (o >> 9) & 3, ct = (o >> 11) & 3, wc = (o >> 13) & 1;
      int row = ks * 32 + (l >> 4) * 8 + j;
      int col = wc * 64 + ct * 16 + (l & 15);
      Wb[i] = f2bf(W[((size_t)layer << 14) + row * DF + col]);
    }
  }
}

// LDS counting-sort of an 8192-edge chunk into dst-buckets; burst-append to fixed regions
__global__ void __launch_bounds__(256) bucket_fill_k(const int* __restrict__ src,
                                                     const int* __restrict__ dst,
                                                     int* __restrict__ bcur,
                                                     int* __restrict__ ebuck, int nE) {
  __shared__ int hist[NBK];
  __shared__ int base[NBK];
  __shared__ int gbase[NBK];
  __shared__ int lpack[CHUNK];
  __shared__ unsigned char lbk[CHUNK];
  int e0 = blockIdx.x * CHUNK;
  int cnt = nE - e0; if (cnt > CHUNK) cnt = CHUNK;
  hist[threadIdx.x] = 0;
  __syncthreads();
  for (int i = threadIdx.x; i < cnt; i += 256)
    atomicAdd(&hist[dst[e0 + i] >> 8], 1);
  __syncthreads();
  int t = threadIdx.x;
  base[t] = hist[t];
  __syncthreads();
  for (int ofs = 1; ofs < NBK; ofs <<= 1) {
    int tv = (t >= ofs) ? base[t - ofs] : 0;
    __syncthreads();
    base[t] += tv;
    __syncthreads();
  }
  int excl = base[t] - hist[t];
  __syncthreads();
  base[t] = excl;
  hist[t] = 0;
  __syncthreads();
  for (int i = threadIdx.x; i < cnt; i += 256) {
    int d = dst[e0 + i], s = src[e0 + i];
    int bk = d >> 8;
    int pos = base[bk] + atomicAdd(&hist[bk], 1);
    lpack[pos] = (s << 8) | (d & 255);
    lbk[pos] = (unsigned char)bk;
  }
  __syncthreads();
  int c = hist[t];
  gbase[t] = c > 0 ? (t * CAP + atomicAdd(&bcur[t], c)) : 0;
  __syncthreads();
  for (int i = threadIdx.x; i < cnt; i += 256) {
    int bk = lbk[i];
    ebuck[gbase[bk] + (i - base[bk])] = lpack[i];
  }
}

// 3 independent small exclusive scans in one launch (block 0..2)
__global__ void __launch_bounds__(1024) scan3_k(
    const int* __restrict__ bcur, int* __restrict__ boff2, int NBUCK,
    const int* __restrict__ pcnt, int* __restrict__ poff, int* __restrict__ pcur,
    const int* __restrict__ icnt, int* __restrict__ ioff, int* __restrict__ icur, int G) {
  const int* in; int* out; int* cur; int n;
  if (blockIdx.x == 0)      { in = bcur; out = boff2; cur = nullptr; n = NBUCK; }
  else if (blockIdx.x == 1) { in = pcnt; out = poff;  cur = pcur;    n = G; }
  else                      { in = icnt; out = ioff;  cur = icur;    n = G; }
  __shared__ int sh[1024];
  int v = (threadIdx.x < (unsigned)n) ? in[threadIdx.x] : 0;
  sh[threadIdx.x] = v;
  __syncthreads();
  for (int ofs = 1; ofs < 1024; ofs <<= 1) {
    int t = (threadIdx.x >= (unsigned)ofs) ? sh[threadIdx.x - ofs] : 0;
    __syncthreads();
    sh[threadIdx.x] += t;
    __syncthreads();
  }
  if (threadIdx.x < (unsigned)n) {
    int ex = sh[threadIdx.x] - v;
    out[threadIdx.x] = ex;
    if (cur) cur[threadIdx.x] = ex;
  }
  if (threadIdx.x == 0) out[n] = sh[1023];
}

// per bucket: local hist -> rowoff + dis + fine-sorted epack={src,dst}, LDS-only atomics
__global__ void __launch_bounds__(256) csr_build_k(const int* __restrict__ bcnt,
                                                   const int* __restrict__ boff2,
                                                   const int* __restrict__ ebuck,
                                                   int* __restrict__ rowoff,
                                                   float* __restrict__ dis,
                                                   int2* __restrict__ epack,
                                                   int N, int NBUCK) {
  int b = blockIdx.x;
  int cnt = bcnt[b];
  int ob = boff2[b];
  const int* ebk = ebuck + (size_t)b * CAP;
  int node0 = b << 8;
  __shared__ int hist[NBK];
  __shared__ int lbase[NBK];
  int t = threadIdx.x;
  hist[t] = 0;
  __syncthreads();
  for (int i = t; i < cnt; i += 256)
    atomicAdd(&hist[ebk[i] & 255], 1);
  __syncthreads();
  int v = hist[t];
  lbase[t] = v;
  __syncthreads();
  for (int ofs = 1; ofs < NBK; ofs <<= 1) {
    int tv = (t >= ofs) ? lbase[t - ofs] : 0;
    __syncthreads();
    lbase[t] += tv;
    __syncthreads();
  }
  int excl = lbase[t] - v;
  __syncthreads();
  lbase[t] = excl;
  hist[t] = 0;  // reuse as local cursor
  int node = node0 + t;
  if (node < N) {
    rowoff[node] = ob + excl;
    dis[node] = 1.0f / sqrtf((float)v + 1.0f);
  }
  if (b == NBUCK - 1 && t == 0) rowoff[N] = ob + cnt;
  __syncthreads();
  for (int i = t; i < cnt; i += 256) {
    int e = ebk[i];
    int loc = e & 255;
    int pos = ob + lbase[loc] + atomicAdd(&hist[loc], 1);
    int2 w; w.x = e >> 8; w.y = node0 + loc;
    epack[pos] = w;
  }
}

// fused small passes: [0,EN) enorm rewrite; [EN,EN+PB) pool_fill
__global__ void enormpool_k(int2* __restrict__ epack, const float* __restrict__ dis, int E,
                            const int* __restrict__ post_idx, const int* __restrict__ image_idx,
                            const int* __restrict__ batch, int* __restrict__ pcur,
                            int* __restrict__ icur, int* __restrict__ plist,
                            int* __restrict__ ilist, int NP, int NI, int EN) {
  int b = blockIdx.x;
  if (b < EN) {
    int i = b * 256 + threadIdx.x;
    if (i < E) {
      int2 w = epack[i];
      epack[i].y = __float_as_int(dis[w.x] * dis[w.y]);
    }
  } else {
    int i = (b - EN) * 256 + threadIdx.x;
    if (i < NP) {
      int nd = post_idx[i];
      int p = atomicAdd(&pcur[batch[nd]], 1);
      plist[p] = nd;
    } else if (i < NP + NI) {
      int nd = image_idx[i - NP];
      int p = atomicAdd(&icur[batch[nd]], 1);
      ilist[p] = nd;
    }
  }
}

// xwb[r][c] = bf16( sum_k A[r][k] * W[k][c] ); A from f32 (layer0) or bf16 Hb.
template<bool BF16A>
__global__ void __launch_bounds__(256) gemm_mfma_k(const float* __restrict__ A,
                                                   const unsigned short* __restrict__ Ab,
                                                   const unsigned short* __restrict__ Wb,
                                                   unsigned short* __restrict__ xwb, int n) {
  const int w = threadIdx.x >> 6, l = threadIdx.x & 63;
  const int wr = w & 1, wc = w >> 1;
  const int r0 = blockIdx.x * 32 + wr * 16;
  const int row = r0 + (l & 15);
  const int kg = l >> 4;                 // 0..3
  short8v bf[4][4];
  const unsigned short* wp = Wb + (size_t)wc * 8192 + (size_t)l * 8;
#pragma unroll
  for (int ct = 0; ct < 4; ++ct)
#pragma unroll
    for (int ks = 0; ks < 4; ++ks)
      bf[ct][ks] = *(const short8v*)(wp + ((ct * 4 + ks) << 9));
  const bool rok = row < n;
  short8v af[4];
  if constexpr (BF16A) {
    const unsigned short* ap = Ab + (size_t)row * DF + kg * 8;
#pragma unroll
    for (int ks = 0; ks < 4; ++ks)
      af[ks] = rok ? *(const short8v*)(ap + ks * 32) : (short8v)0;
  } else {
    const float* ap = A + (size_t)row * DF + kg * 8;
#pragma unroll
    for (int ks = 0; ks < 4; ++ks) {
      if (rok) {
        float4 lo = *(const float4*)(ap + ks * 32);
        float4 hi = *(const float4*)(ap + ks * 32 + 4);
        short8v t;
        t[0] = (short)f2bf(lo.x); t[1] = (short)f2bf(lo.y);
        t[2] = (short)f2bf(lo.z); t[3] = (short)f2bf(lo.w);
        t[4] = (short)f2bf(hi.x); t[5] = (short)f2bf(hi.y);
        t[6] = (short)f2bf(hi.z); t[7] = (short)f2bf(hi.w);
        af[ks] = t;
      } else af[ks] = (short8v)0;
    }
  }
  f32x4 acc[4];
#pragma unroll
  for (int ct = 0; ct < 4; ++ct) acc[ct] = (f32x4)(0.f);
#pragma unroll
  for (int ks = 0; ks < 4; ++ks)
#pragma unroll
    for (int ct = 0; ct < 4; ++ct)
      acc[ct] = __builtin_amdgcn_mfma_f32_16x16x32_bf16(af[ks], bf[ct][ks], acc[ct], 0, 0, 0);
#pragma unroll
  for (int ct = 0; ct < 4; ++ct) {
    int c = wc * 64 + ct * 16 + (l & 15);
#pragma unroll
    for (int rg = 0; rg < 4; ++rg) {
      int r = r0 + kg * 4 + rg;
      if (r < n) xwb[(size_t)r * DF + c] = f2bf(acc[ct][rg]);
    }
  }
}

// CSR gather: 64 lanes/node = 4 teams x 16 lanes; teams stride edges by 4, 2-stage shfl combine.
__global__ void gather_k(const unsigned short* __restrict__ xwb, const int* __restrict__ rowoff,
                         const int2* __restrict__ epack, const float* __restrict__ dis,
                         const float* __restrict__ b, unsigned short* __restrict__ Hb, int n) {
  int gid = blockIdx.x * 256 + threadIdx.x;
  int node = gid >> 6;
  if (node >= n) return;
  int part = gid & 15;
  int team = (gid >> 4) & 3;
  int beg = rowoff[node], end = rowoff[node + 1];
  float acc[8];
#pragma unroll
  for (int j = 0; j < 8; ++j) acc[j] = 0.f;
  int p = beg + team;
  for (; p + 12 < end; p += 16) {
    int2 q0 = epack[p], q1 = epack[p + 4], q2 = epack[p + 8], q3 = epack[p + 12];
    float e0 = __int_as_float(q0.y), e1 = __int_as_float(q1.y);
    float e2 = __int_as_float(q2.y), e3 = __int_as_float(q3.y);
    u16x8 v0 = *(const u16x8*)(xwb + (size_t)q0.x * DF + part * 8);
    u16x8 v1 = *(const u16x8*)(xwb + (size_t)q1.x * DF + part * 8);
    u16x8 v2 = *(const u16x8*)(xwb + (size_t)q2.x * DF + part * 8);
    u16x8 v3 = *(const u16x8*)(xwb + (size_t)q3.x * DF + part * 8);
#pragma unroll
    for (int j = 0; j < 8; ++j) {
      acc[j] = fmaf(bf2f(v0[j]), e0, acc[j]);
      acc[j] = fmaf(bf2f(v1[j]), e1, acc[j]);
      acc[j] = fmaf(bf2f(v2[j]), e2, acc[j]);
      acc[j] = fmaf(bf2f(v3[j]), e3, acc[j]);
    }
  }
  for (; p < end; p += 4) {
    int2 q = epack[p];
    float e = __int_as_float(q.y);
    u16x8 v = *(const u16x8*)(xwb + (size_t)q.x * DF + part * 8);
#pragma unroll
    for (int j = 0; j < 8; ++j) acc[j] = fmaf(bf2f(v[j]), e, acc[j]);
  }
  // combine 4 teams within the 64-lane wave: lane L += L+32, then += L+16
#pragma unroll
  for (int j = 0; j < 8; ++j) acc[j] += __shfl_down(acc[j], 32, 64);
#pragma unroll
  for (int j = 0; j < 8; ++j) acc[j] += __shfl_down(acc[j], 16, 64);
  if (team == 0) {
    float dd = dis[node], sn = dd * dd;
    u16x8 xv = *(const u16x8*)(xwb + (size_t)node * DF + part * 8);
    const float* bp = b + part * 8;
    u16x8 o;
#pragma unroll
    for (int j = 0; j < 8; ++j) {
      float r = fmaf(bf2f(xv[j]), sn, acc[j]) + bp[j];
      r = LEAKY(r);
      o[j] = f2bf(r);
    }
    *(u16x8*)(Hb + (size_t)node * DF + part * 8) = o;
  }
}

// fused post pass: blocks [0,PGB) psum, [PGB,2*PGB) isum, [2*PGB,2*PGB+SB) bn_stats
__global__ void post_k(const unsigned short* __restrict__ Hb,
                       const int* __restrict__ goff_p, const int* __restrict__ mlist_p,
                       const int* __restrict__ goff_i, const int* __restrict__ mlist_i,
                       float* __restrict__ psum, float* __restrict__ isum,
                       float* __restrict__ bns, int n, int PGB, int SB) {
  int b = blockIdx.x;
  if (b < 2 * PGB) {
    int which = b >= PGB;
    int bb = which ? b - PGB : b;
    const int* goff  = which ? goff_i  : goff_p;
    const int* mlist = which ? mlist_i : mlist_p;
    float* out       = which ? isum    : psum;
    int g = bb / PSPLIT, sub = bb % PSPLIT;
    int part = threadIdx.x & 31, slot = threadIdx.x >> 5;
    int beg = goff[g], end = goff[g + 1];
    float4 acc = make_float4(0.f, 0.f, 0.f, 0.f);
    for (int j = beg + sub * 8 + slot; j < end; j += PSPLIT * 8) {
      u16x4 v = *(const u16x4*)(Hb + (size_t)mlist[j] * DF + part * 4);
      acc.x += bf2f(v[0]); acc.y += bf2f(v[1]); acc.z += bf2f(v[2]); acc.w += bf2f(v[3]);
    }
    __shared__ float4 sh[256];
    sh[threadIdx.x] = acc;
    __syncthreads();
    for (int ofs = 128; ofs >= 32; ofs >>= 1) {
      if (threadIdx.x < (unsigned)ofs) {
        float4 o = sh[threadIdx.x + ofs];
        float4 a = sh[threadIdx.x];
        a.x += o.x; a.y += o.y; a.z += o.z; a.w += o.w;
        sh[threadIdx.x] = a;
      }
      __syncthreads();
    }
    if (threadIdx.x < 32) {
      float4 a = sh[threadIdx.x];
      float* o = out + (size_t)g * DF + part * 4;
      atomicAdd(o + 0, a.x);
      atomicAdd(o + 1, a.y);
      atomicAdd(o + 2, a.z);
      atomicAdd(o + 3, a.w);
    }
  } else {
    int sb = b - 2 * PGB;
    int c = threadIdx.x & (DF - 1);
    int half = threadIdx.x >> 7;
    float s = 0.f, q = 0.f;
    for (int r = sb * 2 + half; r < n; r += SB * 2) {
      float v = bf2f(Hb[(size_t)r * DF + c]);
      s += v; q += v * v;
    }
    __shared__ float ls[256], lq[256];
    ls[threadIdx.x] = s; lq[threadIdx.x] = q;
    __syncthreads();
    if (half == 0) {
      atomicAdd(&bns[c], ls[c] + ls[c + DF]);
      atomicAdd(&bns[DF + c], lq[c] + lq[c + DF]);
    }
  }
}

// head layer 1 (folds bn_final): 512 threads, 4-way split-K
__global__ void __launch_bounds__(512) head1_k(const float* __restrict__ psum,
                        const int* __restrict__ pcnt,
                        const float* __restrict__ isum, const int* __restrict__ icnt,
                        const float* __restrict__ bns, const float* __restrict__ hbn_gamma,
                        const float* __restrict__ hbn_beta, int nN,
                        const float* __restrict__ gf_w1, const float* __restrict__ gf_b1,
                        const float* __restrict__ gf_w2, const float* __restrict__ gf_b2,
                        float* __restrict__ hbuf) {
  int g = blockIdx.x;
  int j = threadIdx.x & 127, kq = threadIdx.x >> 7;  // 4 K-quarters
  __shared__ float comb[4 * DF];
  __shared__ float part[512];
  __shared__ float t1[DF];
  if (kq == 0) {
    float m = bns[j] / (float)nN;
    float var = bns[DF + j] / (float)nN - m * m;
    if (var < 0.f) var = 0.f;
    float sc = hbn_gamma[j] / sqrtf(var + 1e-5f);
    float sh = hbn_beta[j] - m * sc;
    int pc = pcnt[g], ic = icnt[g];
    float pf = pc > 0 ? (psum[(size_t)g * DF + j] / (float)pc) * sc + sh : 0.f;
    float im = ic > 0 ? (isum[(size_t)g * DF + j] / (float)ic) * sc + sh : 0.f;
    comb[j] = pf;
    comb[DF + j] = im;
    comb[2 * DF + j] = pf - im;
    comb[3 * DF + j] = pf * im;
  }
  __syncthreads();
  float acc = 0.f;
  const float* w1 = gf_w1 + (size_t)kq * 128 * DF + j;
#pragma unroll 8
  for (int kk = 0; kk < 128; ++kk)
    acc = fmaf(comb[kq * 128 + kk], w1[(size_t)kk * DF], acc);
  part[threadIdx.x] = acc;
  __syncthreads();
  if (kq == 0)
    t1[j] = LEAKY(gf_b1[j] + part[j] + part[128 + j] + part[256 + j] + part[384 + j]);
  __syncthreads();
  acc = 0.f;
  const float* w2 = gf_w2 + (size_t)kq * 32 * DF + j;
#pragma unroll 8
  for (int kk = 0; kk < 32; ++kk)
    acc = fmaf(t1[kq * 32 + kk], w2[(size_t)kk * DF], acc);
  part[threadIdx.x] = acc;
  __syncthreads();
  if (kq == 0)
    hbuf[(size_t)g * DF + j] = gf_b2[j] + part[j] + part[128 + j] + part[256 + j] + part[384 + j];
}

// BN2 stats: one block, 1024 threads = 8 row-slots x 128 cols -> ss2 scale/shift
__global__ void __launch_bounds__(1024) bn2_k(const float* __restrict__ hbuf,
                      const float* __restrict__ gamma, const float* __restrict__ beta,
                      float* __restrict__ ss2, int G) {
  int c = threadIdx.x & 127, slot = threadIdx.x >> 7;  // 8 slots
  float s = 0.f, q = 0.f;
  for (int r = slot; r < G; r += 8) {
    float v = hbuf[(size_t)r * DF + c];
    s += v; q += v * v;
  }
  __shared__ float ls[1024], lq[1024];
  ls[threadIdx.x] = s; lq[threadIdx.x] = q;
  __syncthreads();
  for (int ofs = 512; ofs >= 128; ofs >>= 1) {
    if (threadIdx.x < (unsigned)ofs) {
      ls[threadIdx.x] += ls[threadIdx.x + ofs];
      lq[threadIdx.x] += lq[threadIdx.x + ofs];
    }
    __syncthreads();
  }
  if (threadIdx.x < 128) {
    float m = ls[c] / (float)G;
    float var = lq[c] / (float)G - m * m;
    if (var < 0.f) var = 0.f;
    float sc = gamma[c] / sqrtf(var + 1e-5f);
    ss2[c] = sc;
    ss2[DF + c] = beta[c] - m * sc;
  }
}

// head2: 512 threads, split-K at every stage. BN2-apply, 128->64, 64->32, 32->2.
__global__ void __launch_bounds__(512) head2_k(const float* __restrict__ hbuf,
                        const float* __restrict__ ss2,
                        const float* __restrict__ fl_w1, const float* __restrict__ fl_b1,
                        const float* __restrict__ fl_w2, const float* __restrict__ fl_b2,
                        const float* __restrict__ out_w, const float* __restrict__ out_b,
                        float* __restrict__ d_out, int G) {
  int g = blockIdx.x, t = threadIdx.x;
  __shared__ float hb[DF], part[512], t1[64], ov[32];
  if (t < DF) hb[t] = hbuf[(size_t)g * DF + t] * ss2[t] + ss2[DF + t];
  __syncthreads();
  {
    int j = t & 63, kq = t >> 6;
    float acc = 0.f;
    const float* w = fl_w1 + (size_t)kq * 16 * 64 + j;
#pragma unroll
    for (int kk = 0; kk < 16; ++kk)
      acc = fmaf(hb[kq * 16 + kk], w[(size_t)kk * 64], acc);
    part[t] = acc;
  }
  __syncthreads();
  if (t < 64) {
    float s = fl_b1[t];
#pragma unroll
    for (int i = 0; i < 8; ++i) s += part[i * 64 + t];
    t1[t] = LEAKY(s);
  }
  __syncthreads();
  {
    int j = t & 31, kq = t >> 5;
    float acc = 0.f;
    const float* w = fl_w2 + (size_t)kq * 4 * 32 + j;
#pragma unroll
    for (int kk = 0; kk < 4; ++kk)
      acc = fmaf(t1[kq * 4 + kk], w[(size_t)kk * 32], acc);
    part[t] = acc;
  }
  __syncthreads();
  if (t < 32) {
    float s = fl_b2[t];
#pragma unroll
    for (int i = 0; i < 16; ++i) s += part[i * 32 + t];
    d_out[(size_t)g * 32 + t] = s;
    ov[t] = s;
  }
  __syncthreads();
  if (t < 64) {
    int j = t & 1, kq = t >> 1;
    part[t] = ov[kq] * out_w[(size_t)kq * 2 + j];
  }
  __syncthreads();
  if (t < 2) {
    float s = out_b[t];
#pragma unroll
    for (int i = 0; i < 32; ++i) s += part[i * 2 + t];
    d_out[(size_t)G * 32 + (size_t)g * 2 + t] = s;
  }
}

extern "C" void kernel_launch(void* const* d_in, const int* in_sizes, int n_in,
                              void* d_out, int out_size, void* d_ws, size_t ws_size,
                              hipStream_t stream) {
  const float* x         = (const float*)d_in[0];
  const float* W_gnn     = (const float*)d_in[1];
  const float* b_gnn     = (const float*)d_in[2];
  const float* hbn_gamma = (const float*)d_in[3];
  const float* hbn_beta  = (const float*)d_in[4];
  const float* gf_w1     = (const float*)d_in[5];
  const float* gf_b1     = (const float*)d_in[6];
  const float* gf_w2     = (const float*)d_in[7];
  const float* gf_b2     = (const float*)d_in[8];
  const float* bn2_gamma = (const float*)d_in[9];
  const float* bn2_beta  = (const float*)d_in[10];
  const float* fl_w1     = (const float*)d_in[11];
  const float* fl_b1     = (const float*)d_in[12];
  const float* fl_w2     = (const float*)d_in[13];
  const float* fl_b2     = (const float*)d_in[14];
  const float* out_w     = (const float*)d_in[15];
  const float* out_b     = (const float*)d_in[16];
  const int* edge_index  = (const int*)d_in[17];
  const int* post_idx    = (const int*)d_in[18];
  const int* image_idx   = (const int*)d_in[19];
  const int* batch_vec   = (const int*)d_in[20];

  const int N  = in_sizes[20];
  const int E  = in_sizes[17] / 2;
  const int NP = in_sizes[18];
  const int NI = in_sizes[19];
  const int G  = out_size / 34;           // out: G*32 + prob: G*2
  const int L  = in_sizes[1] / (DF * DF);
  const int* src  = edge_index;
  const int* dstp = edge_index + E;
  const int NBUCK = (N + 255) >> 8;       // 256-node buckets
  const int PB = (NP + NI + 255) / 256;
  const int WT = L * DF * DF;
  const int WB = (WT + 255) / 256;
  const int GB = (N + 31) / 32;           // gemm blocks
  const int EN = (E + 255) / 256;         // enorm blocks
  const int PGB = G * PSPLIT;
  const int SB = 256;                     // bn_stats blocks

  char* ws = (char*)d_ws;
  size_t off = 0;
  auto alloc = [&](size_t b) { size_t o = off; off += (b + 255) & ~(size_t)255; return o; };
  // ---- zero-initialized region (single memset) ----
  size_t zero_beg = off;
  int*   bcur   = (int*)(ws + alloc((size_t)NBK * 4));
  float* bns    = (float*)(ws + alloc(256 * 4));
  float* psum   = (float*)(ws + alloc((size_t)G * DF * 4));
  float* isum   = (float*)(ws + alloc((size_t)G * DF * 4));
  int*   pcnt   = (int*)(ws + alloc((size_t)G * 4));
  int*   icnt   = (int*)(ws + alloc((size_t)G * 4));
  size_t zero_bytes = off - zero_beg;
  // ---- rest ----
  float* dis    = (float*)(ws + alloc((size_t)N * 4));
  int*   rowoff = (int*)(ws + alloc((size_t)(N + 1) * 4));
  int2*  epack  = (int2*)(ws + alloc((size_t)E * 8));
  int*   ebuck  = (int*)(ws + alloc((size_t)NBUCK * CAP * 4));
  int*   boff2  = (int*)(ws + alloc((size_t)(NBK + 1) * 4));
  unsigned short* Wb  = (unsigned short*)(ws + alloc((size_t)WT * 2));
  unsigned short* xwb = (unsigned short*)(ws + alloc((size_t)N * DF * 2));
  unsigned short* Hb  = (unsigned short*)(ws + alloc((size_t)N * DF * 2));
  int*   poff   = (int*)(ws + alloc((size_t)(G + 1) * 4));
  int*   ioff   = (int*)(ws + alloc((size_t)(G + 1) * 4));
  int*   pcur   = (int*)(ws + alloc((size_t)G * 4));
  int*   icur   = (int*)(ws + alloc((size_t)G * 4));
  int*   plist  = (int*)(ws + alloc((size_t)NP * 4));
  int*   ilist  = (int*)(ws + alloc((size_t)NI * 4));
  float* hbuf   = (float*)(ws + alloc((size_t)G * DF * 4));
  float* ss2    = (float*)(ws + alloc(256 * 4));

  hipMemsetAsync(ws + zero_beg, 0, zero_bytes, stream);

  // bucket sort edges into fixed-capacity regions (no pre-histogram pass)
  bucket_fill_k<<<(E + CHUNK - 1) / CHUNK, 256, 0, stream>>>(src, dstp, bcur, ebuck, E);
  // pool counts + castW (independent of buckets)
  fusedA_k<<<PB + WB, 256, 0, stream>>>(post_idx, image_idx, batch_vec, pcnt, icnt,
                                        W_gnn, Wb, NP, NI, WT, PB);
  // scans: bucket counts -> boff2, pool counts -> offsets+cursors
  scan3_k<<<3, 1024, 0, stream>>>(bcur, boff2, NBUCK, pcnt, poff, pcur, icnt, ioff, icur, G);
  // per-bucket CSR build (rowoff + dis + fine-sorted epack)
  csr_build_k<<<NBUCK, 256, 0, stream>>>(bcur, boff2, ebuck, rowoff, dis, epack, N, NBUCK);
  // enorm rewrite + pool fill (both tiny memory passes)
  enormpool_k<<<EN + PB, 256, 0, stream>>>(epack, dis, E, post_idx, image_idx, batch_vec,
                                           pcur, icur, plist, ilist, NP, NI, EN);

  // GNN layers (bf16 MFMA gemm + bf16 gather reads, f32 accumulate)
  for (int l = 0; l < L; ++l) {
    if (l == 0)
      gemm_mfma_k<false><<<GB, 256, 0, stream>>>(x, nullptr,
          Wb + (size_t)l * DF * DF, xwb, N);
    else
      gemm_mfma_k<true><<<GB, 256, 0, stream>>>(nullptr, Hb,
          Wb + (size_t)l * DF * DF, xwb, N);
    gather_k<<<(N * 64 + 255) / 256, 256, 0, stream>>>(xwb, rowoff, epack, dis,
                                                       b_gnn + (size_t)l * DF, Hb, N);
  }

  // fused post: pooled sums + BN stats
  post_k<<<2 * PGB + SB, 256, 0, stream>>>(Hb, poff, plist, ioff, ilist,
                                           psum, isum, bns, N, PGB, SB);

  // head
  head1_k<<<G, 512, 0, stream>>>(psum, pcnt, isum, icnt, bns, hbn_gamma, hbn_beta, N,
                                 gf_w1, gf_b1, gf_w2, gf_b2, hbuf);
  bn2_k<<<1, 1024, 0, stream>>>(hbuf, bn2_gamma, bn2_beta, ss2, G);
  head2_k<<<G, 512, 0, stream>>>(hbuf, ss2, fl_w1, fl_b1, fl_w2, fl_b2, out_w, out_b,
                                 (float*)d_out, G);
}

// Round 15
// 232.362 us; speedup vs baseline: 1.0259x; 1.0259x over previous
//
#include <hip/hip_runtime.h>
#include <hip/hip_bf16.h>
#include <math.h>

#define DF 128
#define PSPLIT 4
#define CHUNK 8192
#define NBK 256
#define CAP 6144   // per-bucket edge capacity (mean ~4082 for E=800K/196 buckets; huge margin)
#define LEAKY(x) ((x) > 0.f ? (x) : 0.01f * (x))

typedef __attribute__((ext_vector_type(8))) short short8v;   // 8 bf16 in 4 VGPRs
typedef __attribute__((ext_vector_type(4))) float f32x4;
typedef __attribute__((ext_vector_type(4))) unsigned short u16x4;
typedef __attribute__((ext_vector_type(8))) unsigned short u16x8;

static __device__ __forceinline__ unsigned short f2bf(float f) {
  unsigned u = __float_as_uint(f);
  unsigned r = u + 0x7fffu + ((u >> 16) & 1u);   // RNE
  return (unsigned short)(r >> 16);
}
static __device__ __forceinline__ float bf2f(unsigned short b) {
  return __uint_as_float(((unsigned)b) << 16);
}

// fused A: [0,PB) pool counts; [PB,PB+WB) castW (fragment order)
__global__ void fusedA_k(const int* __restrict__ post_idx, const int* __restrict__ image_idx,
                         const int* __restrict__ batch, int* __restrict__ pcnt,
                         int* __restrict__ icnt,
                         const float* __restrict__ W, unsigned short* __restrict__ Wb,
                         int NP, int NI, int wTotal, int PB) {
  int b = blockIdx.x;
  if (b < PB) {
    int i = b * 256 + threadIdx.x;
    if (i < NP) atomicAdd(&pcnt[batch[post_idx[i]]], 1);
    else if (i < NP + NI) atomicAdd(&icnt[batch[image_idx[i - NP]]], 1);
  } else {
    int i = (b - PB) * 256 + threadIdx.x;
    if (i < wTotal) {
      int layer = i >> 14, o = i & 16383;
      int j = o & 7, l = (o >> 3) & 63, ks = (o >> 9) & 3, ct = (o >> 11) & 3, wc = (o >> 13) & 1;
      int row = ks * 32 + (l >> 4) * 8 + j;
      int col = wc * 64 + ct * 16 + (l & 15);
      Wb[i] = f2bf(W[((size_t)layer << 14) + row * DF + col]);
    }
  }
}

// LDS counting-sort of an 8192-edge chunk into dst-buckets; burst-append to fixed regions
__global__ void __launch_bounds__(256) bucket_fill_k(const int* __restrict__ src,
                                                     const int* __restrict__ dst,
                                                     int* __restrict__ bcur,
                                                     int* __restrict__ ebuck, int nE) {
  __shared__ int hist[NBK];
  __shared__ int base[NBK];
  __shared__ int gbase[NBK];
  __shared__ int lpack[CHUNK];
  __shared__ unsigned char lbk[CHUNK];
  int e0 = blockIdx.x * CHUNK;
  int cnt = nE - e0; if (cnt > CHUNK) cnt = CHUNK;
  hist[threadIdx.x] = 0;
  __syncthreads();
  for (int i = threadIdx.x; i < cnt; i += 256)
    atomicAdd(&hist[dst[e0 + i] >> 8], 1);
  __syncthreads();
  int t = threadIdx.x;
  base[t] = hist[t];
  __syncthreads();
  for (int ofs = 1; ofs < NBK; ofs <<= 1) {
    int tv = (t >= ofs) ? base[t - ofs] : 0;
    __syncthreads();
    base[t] += tv;
    __syncthreads();
  }
  int excl = base[t] - hist[t];
  __syncthreads();
  base[t] = excl;
  hist[t] = 0;
  __syncthreads();
  for (int i = threadIdx.x; i < cnt; i += 256) {
    int d = dst[e0 + i], s = src[e0 + i];
    int bk = d >> 8;
    int pos = base[bk] + atomicAdd(&hist[bk], 1);
    lpack[pos] = (s << 8) | (d & 255);
    lbk[pos] = (unsigned char)bk;
  }
  __syncthreads();
  int c = hist[t];
  gbase[t] = c > 0 ? (t * CAP + atomicAdd(&bcur[t], c)) : 0;
  __syncthreads();
  for (int i = threadIdx.x; i < cnt; i += 256) {
    int bk = lbk[i];
    ebuck[gbase[bk] + (i - base[bk])] = lpack[i];
  }
}

// 3 independent small exclusive scans in one launch (block 0..2)
__global__ void __launch_bounds__(1024) scan3_k(
    const int* __restrict__ bcur, int* __restrict__ boff2, int NBUCK,
    const int* __restrict__ pcnt, int* __restrict__ poff, int* __restrict__ pcur,
    const int* __restrict__ icnt, int* __restrict__ ioff, int* __restrict__ icur, int G) {
  const int* in; int* out; int* cur; int n;
  if (blockIdx.x == 0)      { in = bcur; out = boff2; cur = nullptr; n = NBUCK; }
  else if (blockIdx.x == 1) { in = pcnt; out = poff;  cur = pcur;    n = G; }
  else                      { in = icnt; out = ioff;  cur = icur;    n = G; }
  __shared__ int sh[1024];
  int v = (threadIdx.x < (unsigned)n) ? in[threadIdx.x] : 0;
  sh[threadIdx.x] = v;
  __syncthreads();
  for (int ofs = 1; ofs < 1024; ofs <<= 1) {
    int t = (threadIdx.x >= (unsigned)ofs) ? sh[threadIdx.x - ofs] : 0;
    __syncthreads();
    sh[threadIdx.x] += t;
    __syncthreads();
  }
  if (threadIdx.x < (unsigned)n) {
    int ex = sh[threadIdx.x] - v;
    out[threadIdx.x] = ex;
    if (cur) cur[threadIdx.x] = ex;
  }
  if (threadIdx.x == 0) out[n] = sh[1023];
}

// per bucket: local hist -> rowoff + dis + fine-sorted epack={src,dst}, LDS-only atomics
__global__ void __launch_bounds__(256) csr_build_k(const int* __restrict__ bcnt,
                                                   const int* __restrict__ boff2,
                                                   const int* __restrict__ ebuck,
                                                   int* __restrict__ rowoff,
                                                   float* __restrict__ dis,
                                                   int2* __restrict__ epack,
                                                   int N, int NBUCK) {
  int b = blockIdx.x;
  int cnt = bcnt[b];
  int ob = boff2[b];
  const int* ebk = ebuck + (size_t)b * CAP;
  int node0 = b << 8;
  __shared__ int hist[NBK];
  __shared__ int lbase[NBK];
  int t = threadIdx.x;
  hist[t] = 0;
  __syncthreads();
  for (int i = t; i < cnt; i += 256)
    atomicAdd(&hist[ebk[i] & 255], 1);
  __syncthreads();
  int v = hist[t];
  lbase[t] = v;
  __syncthreads();
  for (int ofs = 1; ofs < NBK; ofs <<= 1) {
    int tv = (t >= ofs) ? lbase[t - ofs] : 0;
    __syncthreads();
    lbase[t] += tv;
    __syncthreads();
  }
  int excl = lbase[t] - v;
  __syncthreads();
  lbase[t] = excl;
  hist[t] = 0;  // reuse as local cursor
  int node = node0 + t;
  if (node < N) {
    rowoff[node] = ob + excl;
    dis[node] = 1.0f / sqrtf((float)v + 1.0f);
  }
  if (b == NBUCK - 1 && t == 0) rowoff[N] = ob + cnt;
  __syncthreads();
  for (int i = t; i < cnt; i += 256) {
    int e = ebk[i];
    int loc = e & 255;
    int pos = ob + lbase[loc] + atomicAdd(&hist[loc], 1);
    int2 w; w.x = e >> 8; w.y = node0 + loc;
    epack[pos] = w;
  }
}

// fused small passes: [0,EN) enorm rewrite; [EN,EN+PB) pool_fill
__global__ void enormpool_k(int2* __restrict__ epack, const float* __restrict__ dis, int E,
                            const int* __restrict__ post_idx, const int* __restrict__ image_idx,
                            const int* __restrict__ batch, int* __restrict__ pcur,
                            int* __restrict__ icur, int* __restrict__ plist,
                            int* __restrict__ ilist, int NP, int NI, int EN) {
  int b = blockIdx.x;
  if (b < EN) {
    int i = b * 256 + threadIdx.x;
    if (i < E) {
      int2 w = epack[i];
      epack[i].y = __float_as_int(dis[w.x] * dis[w.y]);
    }
  } else {
    int i = (b - EN) * 256 + threadIdx.x;
    if (i < NP) {
      int nd = post_idx[i];
      int p = atomicAdd(&pcur[batch[nd]], 1);
      plist[p] = nd;
    } else if (i < NP + NI) {
      int nd = image_idx[i - NP];
      int p = atomicAdd(&icur[batch[nd]], 1);
      ilist[p] = nd;
    }
  }
}

// xwb[r][c] = bf16( sum_k A[r][k] * W[k][c] ); A from f32 (layer0) or bf16 Hb.
template<bool BF16A>
__global__ void __launch_bounds__(256) gemm_mfma_k(const float* __restrict__ A,
                                                   const unsigned short* __restrict__ Ab,
                                                   const unsigned short* __restrict__ Wb,
                                                   unsigned short* __restrict__ xwb, int n) {
  const int w = threadIdx.x >> 6, l = threadIdx.x & 63;
  const int wr = w & 1, wc = w >> 1;
  const int r0 = blockIdx.x * 32 + wr * 16;
  const int row = r0 + (l & 15);
  const int kg = l >> 4;                 // 0..3
  short8v bf[4][4];
  const unsigned short* wp = Wb + (size_t)wc * 8192 + (size_t)l * 8;
#pragma unroll
  for (int ct = 0; ct < 4; ++ct)
#pragma unroll
    for (int ks = 0; ks < 4; ++ks)
      bf[ct][ks] = *(const short8v*)(wp + ((ct * 4 + ks) << 9));
  const bool rok = row < n;
  short8v af[4];
  if constexpr (BF16A) {
    const unsigned short* ap = Ab + (size_t)row * DF + kg * 8;
#pragma unroll
    for (int ks = 0; ks < 4; ++ks)
      af[ks] = rok ? *(const short8v*)(ap + ks * 32) : (short8v)0;
  } else {
    const float* ap = A + (size_t)row * DF + kg * 8;
#pragma unroll
    for (int ks = 0; ks < 4; ++ks) {
      if (rok) {
        float4 lo = *(const float4*)(ap + ks * 32);
        float4 hi = *(const float4*)(ap + ks * 32 + 4);
        short8v t;
        t[0] = (short)f2bf(lo.x); t[1] = (short)f2bf(lo.y);
        t[2] = (short)f2bf(lo.z); t[3] = (short)f2bf(lo.w);
        t[4] = (short)f2bf(hi.x); t[5] = (short)f2bf(hi.y);
        t[6] = (short)f2bf(hi.z); t[7] = (short)f2bf(hi.w);
        af[ks] = t;
      } else af[ks] = (short8v)0;
    }
  }
  f32x4 acc[4];
#pragma unroll
  for (int ct = 0; ct < 4; ++ct) acc[ct] = (f32x4)(0.f);
#pragma unroll
  for (int ks = 0; ks < 4; ++ks)
#pragma unroll
    for (int ct = 0; ct < 4; ++ct)
      acc[ct] = __builtin_amdgcn_mfma_f32_16x16x32_bf16(af[ks], bf[ct][ks], acc[ct], 0, 0, 0);
#pragma unroll
  for (int ct = 0; ct < 4; ++ct) {
    int c = wc * 64 + ct * 16 + (l & 15);
#pragma unroll
    for (int rg = 0; rg < 4; ++rg) {
      int r = r0 + kg * 4 + rg;
      if (r < n) xwb[(size_t)r * DF + c] = f2bf(acc[ct][rg]);
    }
  }
}

// CSR gather: 32 lanes/node = 2 teams x 16 lanes; teams split edges, shfl combine.
__global__ void gather_k(const unsigned short* __restrict__ xwb, const int* __restrict__ rowoff,
                         const int2* __restrict__ epack, const float* __restrict__ dis,
                         const float* __restrict__ b, unsigned short* __restrict__ Hb, int n) {
  int gid = blockIdx.x * 256 + threadIdx.x;
  int node = gid >> 5;
  if (node >= n) return;
  int part = gid & 15;
  int team = (gid >> 4) & 1;
  int beg = rowoff[node], end = rowoff[node + 1];
  float acc[8];
#pragma unroll
  for (int j = 0; j < 8; ++j) acc[j] = 0.f;
  int p = beg + team;
  for (; p + 6 < end; p += 8) {
    int2 q0 = epack[p], q1 = epack[p + 2], q2 = epack[p + 4], q3 = epack[p + 6];
    float e0 = __int_as_float(q0.y), e1 = __int_as_float(q1.y);
    float e2 = __int_as_float(q2.y), e3 = __int_as_float(q3.y);
    u16x8 v0 = *(const u16x8*)(xwb + (size_t)q0.x * DF + part * 8);
    u16x8 v1 = *(const u16x8*)(xwb + (size_t)q1.x * DF + part * 8);
    u16x8 v2 = *(const u16x8*)(xwb + (size_t)q2.x * DF + part * 8);
    u16x8 v3 = *(const u16x8*)(xwb + (size_t)q3.x * DF + part * 8);
#pragma unroll
    for (int j = 0; j < 8; ++j) {
      acc[j] = fmaf(bf2f(v0[j]), e0, acc[j]);
      acc[j] = fmaf(bf2f(v1[j]), e1, acc[j]);
      acc[j] = fmaf(bf2f(v2[j]), e2, acc[j]);
      acc[j] = fmaf(bf2f(v3[j]), e3, acc[j]);
    }
  }
  for (; p < end; p += 2) {
    int2 q = epack[p];
    float e = __int_as_float(q.y);
    u16x8 v = *(const u16x8*)(xwb + (size_t)q.x * DF + part * 8);
#pragma unroll
    for (int j = 0; j < 8; ++j) acc[j] = fmaf(bf2f(v[j]), e, acc[j]);
  }
#pragma unroll
  for (int j = 0; j < 8; ++j) acc[j] += __shfl_down(acc[j], 16, 32);
  if (team == 0) {
    float dd = dis[node], sn = dd * dd;
    u16x8 xv = *(const u16x8*)(xwb + (size_t)node * DF + part * 8);
    const float* bp = b + part * 8;
    u16x8 o;
#pragma unroll
    for (int j = 0; j < 8; ++j) {
      float r = fmaf(bf2f(xv[j]), sn, acc[j]) + bp[j];
      r = LEAKY(r);
      o[j] = f2bf(r);
    }
    *(u16x8*)(Hb + (size_t)node * DF + part * 8) = o;
  }
}

// fused post pass: blocks [0,PGB) psum, [PGB,2*PGB) isum, [2*PGB,2*PGB+SB) bn_stats
__global__ void post_k(const unsigned short* __restrict__ Hb,
                       const int* __restrict__ goff_p, const int* __restrict__ mlist_p,
                       const int* __restrict__ goff_i, const int* __restrict__ mlist_i,
                       float* __restrict__ psum, float* __restrict__ isum,
                       float* __restrict__ bns, int n, int PGB, int SB) {
  int b = blockIdx.x;
  if (b < 2 * PGB) {
    int which = b >= PGB;
    int bb = which ? b - PGB : b;
    const int* goff  = which ? goff_i  : goff_p;
    const int* mlist = which ? mlist_i : mlist_p;
    float* out       = which ? isum    : psum;
    int g = bb / PSPLIT, sub = bb % PSPLIT;
    int part = threadIdx.x & 31, slot = threadIdx.x >> 5;
    int beg = goff[g], end = goff[g + 1];
    float4 acc = make_float4(0.f, 0.f, 0.f, 0.f);
    for (int j = beg + sub * 8 + slot; j < end; j += PSPLIT * 8) {
      u16x4 v = *(const u16x4*)(Hb + (size_t)mlist[j] * DF + part * 4);
      acc.x += bf2f(v[0]); acc.y += bf2f(v[1]); acc.z += bf2f(v[2]); acc.w += bf2f(v[3]);
    }
    __shared__ float4 sh[256];
    sh[threadIdx.x] = acc;
    __syncthreads();
    for (int ofs = 128; ofs >= 32; ofs >>= 1) {
      if (threadIdx.x < (unsigned)ofs) {
        float4 o = sh[threadIdx.x + ofs];
        float4 a = sh[threadIdx.x];
        a.x += o.x; a.y += o.y; a.z += o.z; a.w += o.w;
        sh[threadIdx.x] = a;
      }
      __syncthreads();
    }
    if (threadIdx.x < 32) {
      float4 a = sh[threadIdx.x];
      float* o = out + (size_t)g * DF + part * 4;
      atomicAdd(o + 0, a.x);
      atomicAdd(o + 1, a.y);
      atomicAdd(o + 2, a.z);
      atomicAdd(o + 3, a.w);
    }
  } else {
    int sb = b - 2 * PGB;
    int c = threadIdx.x & (DF - 1);
    int half = threadIdx.x >> 7;
    float s = 0.f, q = 0.f;
    for (int r = sb * 2 + half; r < n; r += SB * 2) {
      float v = bf2f(Hb[(size_t)r * DF + c]);
      s += v; q += v * v;
    }
    __shared__ float ls[256], lq[256];
    ls[threadIdx.x] = s; lq[threadIdx.x] = q;
    __syncthreads();
    if (half == 0) {
      atomicAdd(&bns[c], ls[c] + ls[c + DF]);
      atomicAdd(&bns[DF + c], lq[c] + lq[c + DF]);
    }
  }
}

// head layer 1 (folds bn_final): 512 threads, 4-way split-K
__global__ void __launch_bounds__(512) head1_k(const float* __restrict__ psum,
                        const int* __restrict__ pcnt,
                        const float* __restrict__ isum, const int* __restrict__ icnt,
                        const float* __restrict__ bns, const float* __restrict__ hbn_gamma,
                        const float* __restrict__ hbn_beta, int nN,
                        const float* __restrict__ gf_w1, const float* __restrict__ gf_b1,
                        const float* __restrict__ gf_w2, const float* __restrict__ gf_b2,
                        float* __restrict__ hbuf) {
  int g = blockIdx.x;
  int j = threadIdx.x & 127, kq = threadIdx.x >> 7;  // 4 K-quarters
  __shared__ float comb[4 * DF];
  __shared__ float part[512];
  __shared__ float t1[DF];
  if (kq == 0) {
    float m = bns[j] / (float)nN;
    float var = bns[DF + j] / (float)nN - m * m;
    if (var < 0.f) var = 0.f;
    float sc = hbn_gamma[j] / sqrtf(var + 1e-5f);
    float sh = hbn_beta[j] - m * sc;
    int pc = pcnt[g], ic = icnt[g];
    float pf = pc > 0 ? (psum[(size_t)g * DF + j] / (float)pc) * sc + sh : 0.f;
    float im = ic > 0 ? (isum[(size_t)g * DF + j] / (float)ic) * sc + sh : 0.f;
    comb[j] = pf;
    comb[DF + j] = im;
    comb[2 * DF + j] = pf - im;
    comb[3 * DF + j] = pf * im;
  }
  __syncthreads();
  float acc = 0.f;
  const float* w1 = gf_w1 + (size_t)kq * 128 * DF + j;
#pragma unroll 8
  for (int kk = 0; kk < 128; ++kk)
    acc = fmaf(comb[kq * 128 + kk], w1[(size_t)kk * DF], acc);
  part[threadIdx.x] = acc;
  __syncthreads();
  if (kq == 0)
    t1[j] = LEAKY(gf_b1[j] + part[j] + part[128 + j] + part[256 + j] + part[384 + j]);
  __syncthreads();
  acc = 0.f;
  const float* w2 = gf_w2 + (size_t)kq * 32 * DF + j;
#pragma unroll 8
  for (int kk = 0; kk < 32; ++kk)
    acc = fmaf(t1[kq * 32 + kk], w2[(size_t)kk * DF], acc);
  part[threadIdx.x] = acc;
  __syncthreads();
  if (kq == 0)
    hbuf[(size_t)g * DF + j] = gf_b2[j] + part[j] + part[128 + j] + part[256 + j] + part[384 + j];
}

// BN2 stats: one block, 1024 threads = 8 row-slots x 128 cols -> ss2 scale/shift
__global__ void __launch_bounds__(1024) bn2_k(const float* __restrict__ hbuf,
                      const float* __restrict__ gamma, const float* __restrict__ beta,
                      float* __restrict__ ss2, int G) {
  int c = threadIdx.x & 127, slot = threadIdx.x >> 7;  // 8 slots
  float s = 0.f, q = 0.f;
  for (int r = slot; r < G; r += 8) {
    float v = hbuf[(size_t)r * DF + c];
    s += v; q += v * v;
  }
  __shared__ float ls[1024], lq[1024];
  ls[threadIdx.x] = s; lq[threadIdx.x] = q;
  __syncthreads();
  for (int ofs = 512; ofs >= 128; ofs >>= 1) {
    if (threadIdx.x < (unsigned)ofs) {
      ls[threadIdx.x] += ls[threadIdx.x + ofs];
      lq[threadIdx.x] += lq[threadIdx.x + ofs];
    }
    __syncthreads();
  }
  if (threadIdx.x < 128) {
    float m = ls[c] / (float)G;
    float var = lq[c] / (float)G - m * m;
    if (var < 0.f) var = 0.f;
    float sc = gamma[c] / sqrtf(var + 1e-5f);
    ss2[c] = sc;
    ss2[DF + c] = beta[c] - m * sc;
  }
}

// head2: 512 threads, split-K at every stage. BN2-apply, 128->64, 64->32, 32->2.
__global__ void __launch_bounds__(512) head2_k(const float* __restrict__ hbuf,
                        const float* __restrict__ ss2,
                        const float* __restrict__ fl_w1, const float* __restrict__ fl_b1,
                        const float* __restrict__ fl_w2, const float* __restrict__ fl_b2,
                        const float* __restrict__ out_w, const float* __restrict__ out_b,
                        float* __restrict__ d_out, int G) {
  int g = blockIdx.x, t = threadIdx.x;
  __shared__ float hb[DF], part[512], t1[64], ov[32];
  if (t < DF) hb[t] = hbuf[(size_t)g * DF + t] * ss2[t] + ss2[DF + t];
  __syncthreads();
  {
    int j = t & 63, kq = t >> 6;
    float acc = 0.f;
    const float* w = fl_w1 + (size_t)kq * 16 * 64 + j;
#pragma unroll
    for (int kk = 0; kk < 16; ++kk)
      acc = fmaf(hb[kq * 16 + kk], w[(size_t)kk * 64], acc);
    part[t] = acc;
  }
  __syncthreads();
  if (t < 64) {
    float s = fl_b1[t];
#pragma unroll
    for (int i = 0; i < 8; ++i) s += part[i * 64 + t];
    t1[t] = LEAKY(s);
  }
  __syncthreads();
  {
    int j = t & 31, kq = t >> 5;
    float acc = 0.f;
    const float* w = fl_w2 + (size_t)kq * 4 * 32 + j;
#pragma unroll
    for (int kk = 0; kk < 4; ++kk)
      acc = fmaf(t1[kq * 4 + kk], w[(size_t)kk * 32], acc);
    part[t] = acc;
  }
  __syncthreads();
  if (t < 32) {
    float s = fl_b2[t];
#pragma unroll
    for (int i = 0; i < 16; ++i) s += part[i * 32 + t];
    d_out[(size_t)g * 32 + t] = s;
    ov[t] = s;
  }
  __syncthreads();
  if (t < 64) {
    int j = t & 1, kq = t >> 1;
    part[t] = ov[kq] * out_w[(size_t)kq * 2 + j];
  }
  __syncthreads();
  if (t < 2) {
    float s = out_b[t];
#pragma unroll
    for (int i = 0; i < 32; ++i) s += part[i * 2 + t];
    d_out[(size_t)G * 32 + (size_t)g * 2 + t] = s;
  }
}

extern "C" void kernel_launch(void* const* d_in, const int* in_sizes, int n_in,
                              void* d_out, int out_size, void* d_ws, size_t ws_size,
                              hipStream_t stream) {
  const float* x         = (const float*)d_in[0];
  const float* W_gnn     = (const float*)d_in[1];
  const float* b_gnn     = (const float*)d_in[2];
  const float* hbn_gamma = (const float*)d_in[3];
  const float* hbn_beta  = (const float*)d_in[4];
  const float* gf_w1     = (const float*)d_in[5];
  const float* gf_b1     = (const float*)d_in[6];
  const float* gf_w2     = (const float*)d_in[7];
  const float* gf_b2     = (const float*)d_in[8];
  const float* bn2_gamma = (const float*)d_in[9];
  const float* bn2_beta  = (const float*)d_in[10];
  const float* fl_w1     = (const float*)d_in[11];
  const float* fl_b1     = (const float*)d_in[12];
  const float* fl_w2     = (const float*)d_in[13];
  const float* fl_b2     = (const float*)d_in[14];
  const float* out_w     = (const float*)d_in[15];
  const float* out_b     = (const float*)d_in[16];
  const int* edge_index  = (const int*)d_in[17];
  const int* post_idx    = (const int*)d_in[18];
  const int* image_idx   = (const int*)d_in[19];
  const int* batch_vec   = (const int*)d_in[20];

  const int N  = in_sizes[20];
  const int E  = in_sizes[17] / 2;
  const int NP = in_sizes[18];
  const int NI = in_sizes[19];
  const int G  = out_size / 34;           // out: G*32 + prob: G*2
  const int L  = in_sizes[1] / (DF * DF);
  const int* src  = edge_index;
  const int* dstp = edge_index + E;
  const int NBUCK = (N + 255) >> 8;       // 256-node buckets
  const int PB = (NP + NI + 255) / 256;
  const int WT = L * DF * DF;
  const int WB = (WT + 255) / 256;
  const int GB = (N + 31) / 32;           // gemm blocks
  const int EN = (E + 255) / 256;         // enorm blocks
  const int PGB = G * PSPLIT;
  const int SB = 256;                     // bn_stats blocks

  char* ws = (char*)d_ws;
  size_t off = 0;
  auto alloc = [&](size_t b) { size_t o = off; off += (b + 255) & ~(size_t)255; return o; };
  // ---- zero-initialized region (single memset) ----
  size_t zero_beg = off;
  int*   bcur   = (int*)(ws + alloc((size_t)NBK * 4));
  float* bns    = (float*)(ws + alloc(256 * 4));
  float* psum   = (float*)(ws + alloc((size_t)G * DF * 4));
  float* isum   = (float*)(ws + alloc((size_t)G * DF * 4));
  int*   pcnt   = (int*)(ws + alloc((size_t)G * 4));
  int*   icnt   = (int*)(ws + alloc((size_t)G * 4));
  size_t zero_bytes = off - zero_beg;
  // ---- rest ----
  float* dis    = (float*)(ws + alloc((size_t)N * 4));
  int*   rowoff = (int*)(ws + alloc((size_t)(N + 1) * 4));
  int2*  epack  = (int2*)(ws + alloc((size_t)E * 8));
  int*   ebuck  = (int*)(ws + alloc((size_t)NBUCK * CAP * 4));
  int*   boff2  = (int*)(ws + alloc((size_t)(NBK + 1) * 4));
  unsigned short* Wb  = (unsigned short*)(ws + alloc((size_t)WT * 2));
  unsigned short* xwb = (unsigned short*)(ws + alloc((size_t)N * DF * 2));
  unsigned short* Hb  = (unsigned short*)(ws + alloc((size_t)N * DF * 2));
  int*   poff   = (int*)(ws + alloc((size_t)(G + 1) * 4));
  int*   ioff   = (int*)(ws + alloc((size_t)(G + 1) * 4));
  int*   pcur   = (int*)(ws + alloc((size_t)G * 4));
  int*   icur   = (int*)(ws + alloc((size_t)G * 4));
  int*   plist  = (int*)(ws + alloc((size_t)NP * 4));
  int*   ilist  = (int*)(ws + alloc((size_t)NI * 4));
  float* hbuf   = (float*)(ws + alloc((size_t)G * DF * 4));
  float* ss2    = (float*)(ws + alloc(256 * 4));

  hipMemsetAsync(ws + zero_beg, 0, zero_bytes, stream);

  // bucket sort edges into fixed-capacity regions (no pre-histogram pass)
  bucket_fill_k<<<(E + CHUNK - 1) / CHUNK, 256, 0, stream>>>(src, dstp, bcur, ebuck, E);
  // pool counts + castW (independent of buckets)
  fusedA_k<<<PB + WB, 256, 0, stream>>>(post_idx, image_idx, batch_vec, pcnt, icnt,
                                        W_gnn, Wb, NP, NI, WT, PB);
  // scans: bucket counts -> boff2, pool counts -> offsets+cursors
  scan3_k<<<3, 1024, 0, stream>>>(bcur, boff2, NBUCK, pcnt, poff, pcur, icnt, ioff, icur, G);
  // per-bucket CSR build (rowoff + dis + fine-sorted epack)
  csr_build_k<<<NBUCK, 256, 0, stream>>>(bcur, boff2, ebuck, rowoff, dis, epack, N, NBUCK);
  // enorm rewrite + pool fill (both tiny memory passes)
  enormpool_k<<<EN + PB, 256, 0, stream>>>(epack, dis, E, post_idx, image_idx, batch_vec,
                                           pcur, icur, plist, ilist, NP, NI, EN);

  // GNN layers (bf16 MFMA gemm + bf16 gather reads, f32 accumulate)
  for (int l = 0; l < L; ++l) {
    if (l == 0)
      gemm_mfma_k<false><<<GB, 256, 0, stream>>>(x, nullptr,
          Wb + (size_t)l * DF * DF, xwb, N);
    else
      gemm_mfma_k<true><<<GB, 256, 0, stream>>>(nullptr, Hb,
          Wb + (size_t)l * DF * DF, xwb, N);
    gather_k<<<(N * 32 + 255) / 256, 256, 0, stream>>>(xwb, rowoff, epack, dis,
                                                       b_gnn + (size_t)l * DF, Hb, N);
  }

  // fused post: pooled sums + BN stats
  post_k<<<2 * PGB + SB, 256, 0, stream>>>(Hb, poff, plist, ioff, ilist,
                                           psum, isum, bns, N, PGB, SB);

  // head
  head1_k<<<G, 512, 0, stream>>>(psum, pcnt, isum, icnt, bns, hbn_gamma, hbn_beta, N,
                                 gf_w1, gf_b1, gf_w2, gf_b2, hbuf);
  bn2_k<<<1, 1024, 0, stream>>>(hbuf, bn2_gamma, bn2_beta, ss2, G);
  head2_k<<<G, 512, 0, stream>>>(hbuf, ss2, fl_w1, fl_b1, fl_w2, fl_b2, out_w, out_b,
                                 (float*)d_out, G);
}